// Round 1
// baseline (685.593 us; speedup 1.0000x reference)
//
#include <hip/hip_runtime.h>

// SNG: sn[b,l] = 8-step majority chain
//   v_0 = 0; v_{i+1} = maj(x[b,i], v_i, r[b,i,l+i]); sn[b,l] = v_8
// where x[b,i] = (num[b]>>i)&1, maj(x,y,r) = x&y | x&r | y&r.
// Derived by unrolling the reference's pipelined scan: module i at time t
// consumes r[b,i,t], and output at t=l+P-1 traces back through r[b,i,l+i].

#define BATCH 1024
#define PBITS 8
#define LBITS 16384
#define TLEN (PBITS + LBITS)   // 16392 ints per r-row

__global__ __launch_bounds__(256) void sng_kernel(const int* __restrict__ num,
                                                  const int* __restrict__ r,
                                                  int* __restrict__ out) {
    const int tid = blockIdx.x * 256 + threadIdx.x;   // one thread = 4 outputs
    const int b = tid >> 12;                          // L/4 = 4096 threads per batch
    const int j = tid & 4095;
    const int l = j << 2;

    const int n = num[b];                             // block-uniform, L1-hot
    const int* rb = r + (size_t)b * PBITS * TLEN;

    int4 v = make_int4(0, 0, 0, 0);
#pragma unroll
    for (int i = 0; i < PBITS; ++i) {
        // row i, elements [l+i, l+i+3]; dword-aligned dwordx4 (OK on CDNA)
        const int4 rv = *reinterpret_cast<const int4*>(rb + (size_t)i * TLEN + l + i);
        const int xb = (n >> i) & 1;                  // 0 or 1; all values stay in {0,1}
        v.x = (xb & (v.x | rv.x)) | (v.x & rv.x);
        v.y = (xb & (v.y | rv.y)) | (v.y & rv.y);
        v.z = (xb & (v.z | rv.z)) | (v.z & rv.z);
        v.w = (xb & (v.w | rv.w)) | (v.w & rv.w);
    }
    reinterpret_cast<int4*>(out)[tid] = v;            // 16B aligned store
}

extern "C" void kernel_launch(void* const* d_in, const int* in_sizes, int n_in,
                              void* d_out, int out_size, void* d_ws, size_t ws_size,
                              hipStream_t stream) {
    const int* num = (const int*)d_in[0];   // [B] int32
    const int* r   = (const int*)d_in[1];   // [B, P, P+L] int32 (0/1)
    int* out = (int*)d_out;                 // [B, L] int32 (0/1)

    const int total_threads = BATCH * LBITS / 4;      // 4,194,304
    const int blocks = total_threads / 256;           // 16,384
    sng_kernel<<<blocks, 256, 0, stream>>>(num, r, out);
}

// Round 2
// 670.433 us; speedup vs baseline: 1.0226x; 1.0226x over previous
//
#include <hip/hip_runtime.h>

// SNG: sn[b,l] = 8-step majority chain (reference scan unrolled):
//   v_0 = 0; v_{i+1} = maj(x[b,i], v_i, r[b,i,l+i]); sn[b,l] = v_8
// maj(x,v,r) with x in {0,1}:  x=1 -> v|r ; x=0 -> v&r
// Branchless with xm = -x (all-ones/all-zero SGPR mask):
//   v = (xm & (v|r)) | (v & r)     (3 VALU ops/elem, xm is scalar)

#define BATCH 1024
#define PBITS 8
#define LBITS 16384
#define TLEN (PBITS + LBITS)   // 16392 ints per r-row; row i, output l reads elem l+i

typedef int v4i __attribute__((ext_vector_type(4)));

__global__ __launch_bounds__(256) void sng_kernel(const int* __restrict__ num,
                                                  const int* __restrict__ r,
                                                  int* __restrict__ out) {
    // b derived from blockIdx only -> num[b] is provably wave-uniform (s_load path)
    const int b = blockIdx.x >> 4;                         // 16 blocks per batch row
    const int j = ((blockIdx.x & 15) << 8) | threadIdx.x;  // 0..4095 within row
    const int l = j << 2;                                  // 4 outputs per thread

    const int nb = num[b];                                 // SGPR
    const int* rb = r + (size_t)b * (PBITS * TLEN) + l;

    // Issue all 8 independent row-loads back-to-back (max MLP), nontemporal
    // (zero-reuse stream; don't allocate in L2/L1).
    v4i rv[PBITS];
#pragma unroll
    for (int i = 0; i < PBITS; ++i)
        rv[i] = __builtin_nontemporal_load(
            reinterpret_cast<const v4i*>(rb + i * (TLEN + 1)));  // +i: diagonal shift

    v4i v = {0, 0, 0, 0};
#pragma unroll
    for (int i = 0; i < PBITS; ++i) {
        const int x = (nb >> i) & 1;
        const v4i xm = {-x, -x, -x, -x};                   // splat of SGPR mask
        v = (xm & (v | rv[i])) | (v & rv[i]);
    }

    const int tid = (b << 12) | j;
    __builtin_nontemporal_store(v, reinterpret_cast<v4i*>(out) + tid);
}

extern "C" void kernel_launch(void* const* d_in, const int* in_sizes, int n_in,
                              void* d_out, int out_size, void* d_ws, size_t ws_size,
                              hipStream_t stream) {
    const int* num = (const int*)d_in[0];   // [B] int32
    const int* r   = (const int*)d_in[1];   // [B, P, P+L] int32 (0/1)
    int* out = (int*)d_out;                 // [B, L] int32 (0/1)

    const int blocks = BATCH * (LBITS / 1024);  // 16 blocks/row * 1024 rows = 16384
    sng_kernel<<<blocks, 256, 0, stream>>>(num, r, out);
}